// Round 8
// baseline (2966.020 us; speedup 1.0000x reference)
//
#include <hip/hip_runtime.h>
#include <math.h>

#define EMBED 512
#define HEADS 8
#define DH 64
#define MM 256
#define LSEG 17
#define NPAD 4352
#define NTOK 4097
#define N0 4096
#define BATCH 4
#define CIN 1536
#define QSCALE 0.125f
#define BH 32   // BATCH*HEADS
#define NSEG 17 // key segments of 256 for a3v

typedef float fp32x4 __attribute__((ext_vector_type(4)));
typedef short bf16x8 __attribute__((ext_vector_type(8)));
typedef short bf16x4 __attribute__((ext_vector_type(4)));
typedef unsigned short u16;

__device__ __forceinline__ unsigned short f2bf(float f) {
  unsigned int u = __float_as_uint(f);
  u += 0x7fffu + ((u >> 16) & 1u);
  return (unsigned short)(u >> 16);
}
__device__ __forceinline__ float bf2f(unsigned short u) {
  return __uint_as_float((unsigned)u << 16);
}

// ---------------- block reduction helpers (blockDim.x == 256) ----------------
__device__ __forceinline__ float block_sum(float v, float* red) {
  #pragma unroll
  for (int o = 1; o < 64; o <<= 1) v += __shfl_xor(v, o);
  int lane = threadIdx.x & 63, wid = threadIdx.x >> 6;
  if (lane == 0) red[wid] = v;
  __syncthreads();
  float r = red[0] + red[1] + red[2] + red[3];
  __syncthreads();
  return r;
}
__device__ __forceinline__ float block_max(float v, float* red) {
  #pragma unroll
  for (int o = 1; o < 64; o <<= 1) v = fmaxf(v, __shfl_xor(v, o));
  int lane = threadIdx.x & 63, wid = threadIdx.x >> 6;
  if (lane == 0) red[wid] = v;
  __syncthreads();
  float r = fmaxf(fmaxf(red[0], red[1]), fmaxf(red[2], red[3]));
  __syncthreads();
  return r;
}

// fp32 -> bf16 convert (n multiple of 8)
__global__ void f2bf_kernel(const float* __restrict__ in, u16* __restrict__ out, int n) {
  int t = (blockIdx.x * 256 + threadIdx.x) * 8;
  if (t >= n) return;
  float4 a = *(const float4*)&in[t];
  float4 b = *(const float4*)&in[t + 4];
  bf16x8 pk;
  pk[0]=(short)f2bf(a.x); pk[1]=(short)f2bf(a.y); pk[2]=(short)f2bf(a.z); pk[3]=(short)f2bf(a.w);
  pk[4]=(short)f2bf(b.x); pk[5]=(short)f2bf(b.y); pk[6]=(short)f2bf(b.z); pk[7]=(short)f2bf(b.w);
  *(bf16x8*)&out[t] = pk;
}

// ------- bf16-MFMA GEMM  C = A(M,K)bf16 @ W(N,K)bf16^T,  64x128 tile --------
// mode 0: relu(acc+bias) -> hbuf fp32 scatter
// mode 1: qkv scatter -> q/k/v bf16
// mode 2: fout += acc+bias (residual)
// mode 3: mode2 + copy full rows (minus cls) to fout2 (conv tmp fp32)
__global__ __launch_bounds__(256) void gemm_abt(
    const u16* __restrict__ A, const u16* __restrict__ W,
    int Mrows, int Ncols, int K, const float* __restrict__ bias,
    float* __restrict__ fout, float* __restrict__ fout2,
    u16* __restrict__ uo0, u16* __restrict__ uo1, u16* __restrict__ uo2,
    int mode)
{
  __shared__ u16 As[64][40];
  __shared__ u16 Ws[128][40];
  int tid = threadIdx.x;
  int lane = tid & 63;
  int wv = tid >> 6;
  int rowBase = blockIdx.y * 64, colBase = blockIdx.x * 128;
  int quad = lane >> 4;
  int l15 = lane & 15;
  int sr = tid >> 2;
  int skc = (tid & 3) * 8;

  fp32x4 acc[8];
  #pragma unroll
  for (int i = 0; i < 8; i++) acc[i] = fp32x4{0,0,0,0};

  for (int kb = 0; kb < K; kb += 32) {
    __syncthreads();
    {
      int grow = rowBase + sr;
      bf16x8 av;
      if (grow < Mrows) av = *(const bf16x8*)&A[(size_t)grow * K + kb + skc];
      else { bf16x8 z = {0,0,0,0,0,0,0,0}; av = z; }
      *(bf16x8*)&As[sr][skc] = av;
    }
    #pragma unroll
    for (int h = 0; h < 2; h++) {
      int r = sr + h * 64;
      *(bf16x8*)&Ws[r][skc] =
          *(const bf16x8*)&W[(size_t)(colBase + r) * K + kb + skc];
    }
    __syncthreads();
    bf16x8 aF = *(const bf16x8*)&As[wv * 16 + l15][quad * 8];
    #pragma unroll
    for (int ct = 0; ct < 8; ct++) {
      bf16x8 bF = *(const bf16x8*)&Ws[ct * 16 + l15][quad * 8];
      acc[ct] = __builtin_amdgcn_mfma_f32_16x16x32_bf16(aF, bF, acc[ct], 0, 0, 0);
    }
  }

  #pragma unroll
  for (int ct = 0; ct < 8; ct++) {
    int col = colBase + ct * 16 + l15;
    #pragma unroll
    for (int i = 0; i < 4; i++) {
      int row = rowBase + wv * 16 + quad * 4 + i;
      if (row >= Mrows) continue;
      float v = acc[ct][i];
      if (mode == 0) {
        v += bias[col];
        v = fmaxf(v, 0.f);
        int b = row / N0, n = row % N0;
        fout[((size_t)b * NTOK + 1 + n) * EMBED + col] = v;
      } else if (mode == 1) {
        int b = row / NPAD, n = row % NPAD;
        int sec = col / EMBED;
        int hh = (col % EMBED) / DH;
        int d = col & 63;
        u16* dst = (sec == 0) ? uo0 : ((sec == 1) ? uo1 : uo2);
        if (sec == 0) v *= QSCALE;
        dst[(((size_t)b * HEADS + hh) * NPAD + n) * DH + d] = f2bf(v);
      } else if (mode == 2) {
        v += bias[col];
        fout[(size_t)row * EMBED + col] += v;
      } else {
        v += bias[col];
        float full = fout[(size_t)row * EMBED + col] + v;
        fout[(size_t)row * EMBED + col] = full;
        int b = row / NTOK, t = row % NTOK;
        if (t > 0) fout2[((size_t)b * N0 + (t - 1)) * EMBED + col] = full;
      }
    }
  }
}

// ---- persistent per-bh pinv chain: z0 + 6 Newton iters (4 GEMMs) + z@kv -----
// ONE workgroup (1024 thr, 16 waves) per bh. KEY (r6 post-mortem): gfx950
// writes stream past L2 (write-through), so any operand round-tripped through
// global memory costs HBM/L3 traffic + latency every step. Fix: the B operand
// lives in LDS across steps. Each step's output C is consumed as the NEXT
// step's B (col-major): each wave holds its full 64x64 C-tile in registers
// (acc[4][4] fp32x4 = 64 VGPR), then after a barrier writes C^T directly back
// into the SAME LDS buffer Bs. Only steps 1 & 4 also write a row-major global
// copy (xR / zR, needed later as A operands). t1/t2 never touch global.
// FP accumulation order per element is identical to the multi-launch version.
__global__ __launch_bounds__(1024, 4) void pinv_chain(
    const u16* __restrict__ a2, const float* __restrict__ denoms,
    u16* __restrict__ zR, u16* __restrict__ zC, u16* __restrict__ xR,
    const u16* __restrict__ kvT, u16* __restrict__ kv2T)
{
  __shared__ __align__(16) u16 Bs[256][264];   // 132 KB (<=160 KB LDS)
  int bh = blockIdx.x;
  size_t moff = (size_t)bh * MM * MM;
  const u16* a2b = a2 + moff;
  int tid = threadIdx.x;
  int lane = tid & 63, wv = tid >> 6, quad = lane >> 4, l15 = lane & 15;
  int wr = wv >> 2, wc = wv & 3;
  int r0 = wr * 64;                  // wave = one 64x64 output tile
  float dinv = 1.f / (denoms[0] * denoms[1]);
  u16* zRb = zR + moff;
  u16* zCb = zC + moff;
  u16* xRb = xR + moff;

  // ---- phase 0: z0 (zCb = a2*dinv, zRb = a2^T*dinv) -- tiles overlay Bs ----
  {
    int g = tid >> 8, t256 = tid & 255;
    u16 (*tile)[72] = (u16 (*)[72])((u16*)Bs + (size_t)g * 64 * 72);
    for (int rep = 0; rep < 4; rep++) {
      int idx4 = rep * 4 + g;
      int i0 = (idx4 >> 2) * 64, j0 = (idx4 & 3) * 64;
      #pragma unroll
      for (int it = 0; it < 4; it++) {
        int idx = it * 1024 + t256 * 4;
        int r = idx >> 6, c = idx & 63;
        bf16x4 v = *(const bf16x4*)&a2b[(size_t)(i0 + r) * MM + j0 + c];
        u16 o[4];
        #pragma unroll
        for (int j = 0; j < 4; j++) o[j] = f2bf(bf2f((unsigned short)v[j]) * dinv);
        *(bf16x4*)&zCb[(size_t)(i0 + r) * MM + j0 + c] = *(bf16x4*)o;
        #pragma unroll
        for (int j = 0; j < 4; j++) tile[c + j][r] = o[j];
      }
      __syncthreads();
      #pragma unroll
      for (int it = 0; it < 4; it++) {
        int idx = it * 1024 + t256 * 4;
        int r = idx >> 6, c = idx & 63;
        u16 o[4] = {tile[r][c], tile[r][c + 1], tile[r][c + 2], tile[r][c + 3]};
        *(bf16x4*)&zRb[(size_t)(j0 + r) * MM + i0 + c] = *(bf16x4*)o;
      }
      __syncthreads();
    }
  }

  // ---- one GEMM step: C = gamma*(sgn*(A@B) + beta*A) ----------------------
  // B is in LDS (Bs[n][k] = B[k][n]); optionally staged from global first.
  // Output written to: CrG (row-major global), CcG (col-major global), and/or
  // back into Bs (as next step's B). All Bs reads complete before the
  // epilogue barrier, so overwriting Bs is safe. In-place CrG==Ab is safe:
  // each (row,col) is read (beta) then written by exactly one thread.
  auto gemmstep = [&](const u16* Ab, const u16* BgSrc,
                      u16* CrG, u16* CcG, bool ldsOut, int Nsize,
                      float beta, float sgn, float gamma) {
    if (BgSrc) {
      for (int i = tid * 8; i < Nsize * MM; i += 8192) {
        int r = i >> 8, c = i & 255;
        *(bf16x8*)&Bs[r][c] = *(const bf16x8*)&BgSrc[(size_t)r * MM + c];
      }
      __syncthreads();
    }
    int c0, nct;
    if (Nsize == MM) { c0 = wc * 64; nct = 4; } else { c0 = wc * 16; nct = 1; }
    fp32x4 acc[4][4];
    #pragma unroll
    for (int rt = 0; rt < 4; rt++)
      #pragma unroll
      for (int ct = 0; ct < 4; ct++) acc[rt][ct] = fp32x4{0,0,0,0};
    for (int kb = 0; kb < 8; kb++) {
      bf16x8 aF[4];
      #pragma unroll
      for (int rt = 0; rt < 4; rt++)
        aF[rt] = *(const bf16x8*)&Ab[(size_t)(r0 + rt * 16 + l15) * MM + kb * 32 + quad * 8];
      #pragma unroll
      for (int ct = 0; ct < 4; ct++) {
        if (ct < nct) {
          bf16x8 bF = *(const bf16x8*)&Bs[c0 + ct * 16 + l15][kb * 32 + quad * 8];
          #pragma unroll
          for (int rt = 0; rt < 4; rt++)
            acc[rt][ct] = __builtin_amdgcn_mfma_f32_16x16x32_bf16(aF[rt], bF, acc[rt][ct], 0, 0, 0);
        }
      }
    }
    __syncthreads();   // all waves done reading Bs; C lives in registers
    #pragma unroll
    for (int rt = 0; rt < 4; rt++)
      #pragma unroll
      for (int ct = 0; ct < 4; ct++) {
        if (ct >= nct) continue;
        int colg = c0 + ct * 16 + l15;
        int rb = r0 + rt * 16 + quad * 4;
        u16 o[4];
        #pragma unroll
        for (int i2 = 0; i2 < 4; i2++) {
          float v = sgn * acc[rt][ct][i2];
          if (beta != 0.f) v += beta * bf2f(Ab[(size_t)(rb + i2) * MM + colg]);
          v *= gamma;
          o[i2] = f2bf(v);
          if (CrG) CrG[(size_t)(rb + i2) * Nsize + colg] = o[i2];
        }
        if (CcG) *(bf16x4*)&CcG[(size_t)colg * MM + rb] = *(bf16x4*)o;
        if (ldsOut) *(bf16x4*)&Bs[colg][rb] = *(bf16x4*)o;
      }
    __syncthreads();   // epilogue LDS writes visible to next step
  };

  for (int it = 0; it < 6; it++) {
    // xz = a2 @ z      (B = z^T: staged from zC on iter 0, else in Bs)
    gemmstep(a2b, it == 0 ? zCb : nullptr, xRb, nullptr, true, MM, 0.f, 1.f, 1.f);
    // t1 = 7x - x@xz   (LDS only)
    gemmstep(xRb, nullptr, nullptr, nullptr, true, MM, 7.f, -1.f, 1.f);
    // t2 = 15x - x@t1  (LDS only)
    gemmstep(xRb, nullptr, nullptr, nullptr, true, MM, 15.f, -1.f, 1.f);
    // z' = 0.25(13z - z@t2)  (zR in-place global + LDS as next iter's B)
    gemmstep(zRb, nullptr, zRb, nullptr, true, MM, 13.f, -1.f, 0.25f);
  }
  // final: kv2T[d][m] = (z @ kv)^T  (stage kvT into Bs; output col-major)
  gemmstep(zRb, kvT + (size_t)bh * MM * DH, nullptr, kv2T + (size_t)bh * MM * DH,
           false, DH, 0.f, 1.f, 1.f);
}

// ---------------- small utility kernels ----------------
__global__ void cls_kernel(const float* __restrict__ cls, float* __restrict__ h) {
  int t = blockIdx.x * blockDim.x + threadIdx.x;
  if (t >= BATCH * EMBED) return;
  int b = t / EMBED, c = t % EMBED;
  h[(size_t)b * NTOK * EMBED + c] = cls[c];
}

__global__ void zero_pad_kernel(u16* __restrict__ xpad) {
  int t = blockIdx.x * blockDim.x + threadIdx.x;
  const int per = 255 * EMBED;
  if (t >= BATCH * per) return;
  int b = t / per, r = t % per;
  xpad[(size_t)b * NPAD * EMBED + r] = 0;
}

// LN -> bf16 padded
__global__ __launch_bounds__(256) void ln_pad_kernel(
    const float* __restrict__ h, const float* __restrict__ g,
    const float* __restrict__ be, u16* __restrict__ xpad)
{
  __shared__ float red[4];
  int row = blockIdx.x;
  int b = row / NTOK, j = row % NTOK;
  const float* x = h + (size_t)row * EMBED;
  int tid = threadIdx.x;
  float v0 = x[tid], v1 = x[tid + 256];
  float mu = block_sum(v0 + v1, red) * (1.f / 512.f);
  float d0 = v0 - mu, d1 = v1 - mu;
  float var = block_sum(d0 * d0 + d1 * d1, red) * (1.f / 512.f);
  float inv = 1.f / sqrtf(var + 1e-5f);
  u16* o = xpad + ((size_t)b * NPAD + 255 + j) * EMBED;
  o[tid]       = f2bf(d0 * inv * g[tid]       + be[tid]);
  o[tid + 256] = f2bf(d1 * inv * g[tid + 256] + be[tid + 256]);
}

__global__ __launch_bounds__(256) void landmarks_kernel(
    const u16* __restrict__ q, const u16* __restrict__ k,
    float* __restrict__ qland, float* __restrict__ kland)
{
  int bh = blockIdx.y;
  int m = blockIdx.x * 4 + (threadIdx.x >> 6);
  int d = threadIdx.x & 63;
  const u16* qb = q + (size_t)bh * NPAD * DH;
  const u16* kb = k + (size_t)bh * NPAD * DH;
  float sq = 0.f, sk = 0.f;
  int base = m * LSEG;
  #pragma unroll
  for (int t = 0; t < LSEG; t++) {
    sq += bf2f(qb[(size_t)(base + t) * DH + d]);
    sk += bf2f(kb[(size_t)(base + t) * DH + d]);
  }
  qland[((size_t)bh * MM + m) * DH + d] = sq * (1.f / LSEG);
  kland[((size_t)bh * MM + m) * DH + d] = sk * (1.f / LSEG);
}

__global__ __launch_bounds__(256) void s2_softmax_kernel(
    const float* __restrict__ qland, const float* __restrict__ kland,
    u16* __restrict__ a2)
{
  __shared__ float qrow[64];
  __shared__ float red[4];
  int bh = blockIdx.y, m = blockIdx.x, tid = threadIdx.x;
  if (tid < 64) qrow[tid] = qland[((size_t)bh * MM + m) * DH + tid];
  __syncthreads();
  const float* kb = kland + (size_t)bh * MM * DH + (size_t)tid * DH;
  float s = 0.f;
  #pragma unroll 16
  for (int d = 0; d < 64; d++) s += qrow[d] * kb[d];
  float mx = block_max(s, red);
  float e = __expf(s - mx);
  float tot = block_sum(e, red);
  a2[((size_t)bh * MM + m) * MM + tid] = f2bf(e / tot);
}

__global__ void init_denom_kernel(float* __restrict__ denoms) {
  if (threadIdx.x < 2) denoms[threadIdx.x] = 0.f;
}

__global__ __launch_bounds__(256) void denom_kernel(
    const u16* __restrict__ a2, float* __restrict__ denoms)
{
  __shared__ float red[4];
  int bh = blockIdx.x, tid = threadIdx.x;
  const u16* A = a2 + (size_t)bh * MM * MM;
  float rs = 0.f, cs = 0.f;
  for (int j = 0; j < MM; j++) rs += bf2f(A[(size_t)tid * MM + j]);
  for (int i = 0; i < MM; i++) cs += bf2f(A[(size_t)i * MM + tid]);
  float mr = block_max(rs, red);
  float mc = block_max(cs, red);
  if (tid == 0) {
    atomicMax((int*)&denoms[0], __float_as_int(mr));
    atomicMax((int*)&denoms[1], __float_as_int(mc));
  }
}

// ---- MFMA a3@v partial flash: block = 64 landmarks x 256-key segment --------
__global__ __launch_bounds__(256) void a3v_part_mfma(
    const float* __restrict__ qland, const u16* __restrict__ k,
    const u16* __restrict__ v, u16* __restrict__ Opart,
    float* __restrict__ mpart, float* __restrict__ lpart)
{
  __shared__ __align__(16) u16 qs[64][40];
  __shared__ __align__(16) u16 ks[256][72];   // reused for P[64][264]
  __shared__ __align__(16) u16 vt[64][72];
  int tid = threadIdx.x;
  int lane = tid & 63, wv = tid >> 6, quad = lane >> 4, l15 = lane & 15;
  int bh = blockIdx.y;
  int ltile = blockIdx.x & 3;
  int seg = blockIdx.x >> 2;
  int l0 = ltile * 64;
  int key0 = seg * 256;
  const float* qb = qland + (size_t)bh * MM * DH;
  const u16* kb = k + (size_t)bh * NPAD * DH;
  const u16* vb = v + (size_t)bh * NPAD * DH;

  {
    int sr = tid >> 2, dc = (tid & 3) * 16;
    const float4* p = (const float4*)&qb[(size_t)(l0 + sr) * DH + dc];
    float4 v0 = p[0], v1 = p[1], v2 = p[2], v3 = p[3];
    float va[16] = {v0.x,v0.y,v0.z,v0.w, v1.x,v1.y,v1.z,v1.w,
                    v2.x,v2.y,v2.z,v2.w, v3.x,v3.y,v3.z,v3.w};
    bf16x8 p0, p1;
    #pragma unroll
    for (int j = 0; j < 8; j++) { p0[j] = (short)f2bf(va[j]); p1[j] = (short)f2bf(va[8 + j]); }
    *(bf16x8*)&qs[sr][dc] = p0;
    *(bf16x8*)&qs[sr][dc + 8] = p1;
  }
  #pragma unroll
  for (int i = 0; i < 16; i++) {
    int idx = i * 1024 + tid * 4;
    int r = idx >> 6, c = idx & 63;
    *(bf16x4*)&ks[r][c] = *(const bf16x4*)&kb[(size_t)(key0 + r) * DH + c];
  }
  __syncthreads();

  fp32x4 sacc[16];
  #pragma unroll
  for (int ct = 0; ct < 16; ct++) sacc[ct] = fp32x4{0,0,0,0};
  bf16x8 aF0 = *(const bf16x8*)&qs[wv * 16 + l15][quad * 8];
  bf16x8 aF1 = *(const bf16x8*)&qs[wv * 16 + l15][32 + quad * 8];
  #pragma unroll
  for (int ct = 0; ct < 16; ct++) {
    bf16x8 b0 = *(const bf16x8*)&ks[ct * 16 + l15][quad * 8];
    bf16x8 b1 = *(const bf16x8*)&ks[ct * 16 + l15][32 + quad * 8];
    sacc[ct] = __builtin_amdgcn_mfma_f32_16x16x32_bf16(aF0, b0, sacc[ct], 0, 0, 0);
    sacc[ct] = __builtin_amdgcn_mfma_f32_16x16x32_bf16(aF1, b1, sacc[ct], 0, 0, 0);
  }

  float mrow[4], lrow[4];
  #pragma unroll
  for (int i = 0; i < 4; i++) {
    float m = -3.0e38f;
    #pragma unroll
    for (int ct = 0; ct < 16; ct++) m = fmaxf(m, sacc[ct][i]);
    #pragma unroll
    for (int o = 1; o < 16; o <<= 1) m = fmaxf(m, __shfl_xor(m, o));
    float s = 0.f;
    #pragma unroll
    for (int ct = 0; ct < 16; ct++) {
      float e = __expf(sacc[ct][i] - m);
      sacc[ct][i] = e;
      s += e;
    }
    #pragma unroll
    for (int o = 1; o < 16; o <<= 1) s += __shfl_xor(s, o);
    mrow[i] = m;
    lrow[i] = s;
  }
  __syncthreads();
  u16* P = &ks[0][0];
  #pragma unroll
  for (int ct = 0; ct < 16; ct++)
    #pragma unroll
    for (int i = 0; i < 4; i++)
      P[(size_t)(wv * 16 + quad * 4 + i) * 264 + ct * 16 + l15] = f2bf(sacc[ct][i]);
  __syncthreads();

  fp32x4 oacc[4] = {fp32x4{0,0,0,0}, fp32x4{0,0,0,0}, fp32x4{0,0,0,0}, fp32x4{0,0,0,0}};
  int dh = tid & 63, kgrp = tid >> 6;
  for (int ch = 0; ch < 4; ch++) {
    if (ch) __syncthreads();
    {
      int kbase = kgrp * 16;
      #pragma unroll
      for (int g = 0; g < 4; g++) {
        u16 pk[4];
        #pragma unroll
        for (int r = 0; r < 4; r++)
          pk[r] = vb[(size_t)(key0 + ch * 64 + kbase + g * 4 + r) * DH + dh];
        *(bf16x4*)&vt[dh][kbase + g * 4] = *(bf16x4*)pk;
      }
    }
    __syncthreads();
    #pragma unroll
    for (int ks2 = 0; ks2 < 2; ks2++) {
      bf16x8 aP = *(const bf16x8*)&P[(size_t)(wv * 16 + l15) * 264 + ch * 64 + ks2 * 32 + quad * 8];
      #pragma unroll
      for (int ct = 0; ct < 4; ct++) {
        bf16x8 bV = *(const bf16x8*)&vt[ct * 16 + l15][ks2 * 32 + quad * 8];
        oacc[ct] = __builtin_amdgcn_mfma_f32_16x16x32_bf16(aP, bV, oacc[ct], 0, 0, 0);
      }
    }
  }

  size_t base = ((size_t)seg * BH + bh) * MM + l0;
  #pragma unroll
  for (int ct = 0; ct < 4; ct++)
    #pragma unroll
    for (int i = 0; i < 4; i++) {
      int row = wv * 16 + quad * 4 + i;
      Opart[(base + row) * DH + ct * 16 + l15] = f2bf(oacc[ct][i]);
    }
  if (l15 == 0) {
    #pragma unroll
    for (int i = 0; i < 4; i++) {
      int row = wv * 16 + quad * 4 + i;
      mpart[base + row] = mrow[i];
      lpart[base + row] = lrow[i];
    }
  }
}

// merge partials -> kv^T (col-major for the z@kv GEMM's B operand)
__global__ __launch_bounds__(256) void a3v_merge_kernel(
    const u16* __restrict__ Opart, const float* __restrict__ mpart,
    const float* __restrict__ lpart, u16* __restrict__ kvT)
{
  int bh = blockIdx.y;
  int lbase = blockIdx.x * 64;
  int d = threadIdx.x & 63, lsub = threadIdx.x >> 6;
  for (int li = lsub; li < 64; li += 4) {
    int lm = lbase + li;
    float M = -3.0e38f;
    #pragma unroll
    for (int s = 0; s < NSEG; s++)
      M = fmaxf(M, mpart[((size_t)s * BH + bh) * MM + lm]);
    float L = 0.f, O = 0.f;
    #pragma unroll
    for (int s = 0; s < NSEG; s++) {
      size_t idx = ((size_t)s * BH + bh) * MM + lm;
      float w = __expf(mpart[idx] - M);
      L += lpart[idx] * w;
      O += bf2f(Opart[idx * DH + d]) * w;
    }
    kvT[((size_t)bh * DH + d) * MM + lm] = f2bf(O / L);
  }
}

// ---- MFMA fused a1-softmax @ kv2T + res-conv(33): 64 rows/block -------------
__global__ __launch_bounds__(256, 2) void attn1_mfma(
    const u16* __restrict__ q, const float* __restrict__ kland,
    const u16* __restrict__ kv2T, const u16* __restrict__ v,
    const float* __restrict__ resw, u16* __restrict__ attn)
{
  __shared__ __align__(16) u16 qs[64][40];
  __shared__ __align__(16) u16 klp[256][72];   // reused: P[64][264], then osm fp32[64][66]
  __shared__ __align__(16) u16 kvs[64][264];   // reused: vwin fp32[96][68]
  __shared__ float wsm[33];
  int tid = threadIdx.x;
  int lane = tid & 63, wv = tid >> 6, quad = lane >> 4, l15 = lane & 15;
  int bh = blockIdx.y, b = bh >> 3, hh = bh & 7;
  int n0 = 255 + blockIdx.x * 64;
  const u16* qb  = q + (size_t)bh * NPAD * DH;
  const float* klb = kland + (size_t)bh * MM * DH;
  const u16* kvb = kv2T + (size_t)bh * DH * MM;
  const u16* vb  = v + (size_t)bh * NPAD * DH;
  if (tid < 33) wsm[tid] = resw[hh * 33 + tid];

  {
    int sr = tid >> 2, dc = (tid & 3) * 16;
    int g = n0 + sr; if (g > NPAD - 1) g = NPAD - 1;
    *(bf16x8*)&qs[sr][dc]     = *(const bf16x8*)&qb[(size_t)g * DH + dc];
    *(bf16x8*)&qs[sr][dc + 8] = *(const bf16x8*)&qb[(size_t)g * DH + dc + 8];
  }
  #pragma unroll
  for (int i = 0; i < 16; i++) {
    int idx = i * 1024 + tid * 4;
    int r = idx >> 6, c = idx & 63;
    float4 vv = *(const float4*)&klb[(size_t)r * DH + c];
    bf16x4 pk = { (short)f2bf(vv.x), (short)f2bf(vv.y), (short)f2bf(vv.z), (short)f2bf(vv.w) };
    *(bf16x4*)&klp[r][c] = pk;
  }
  #pragma unroll
  for (int i = 0; i < 8; i++) {
    int idx = i * 2048 + tid * 8;
    int r = idx >> 8, c = idx & 255;
    *(bf16x8*)&kvs[r][c] = *(const bf16x8*)&kvb[(size_t)r * MM + c];
  }
  __syncthreads();

  fp32x4 sacc[16];
  #pragma unroll
  for (int ct = 0; ct < 16; ct++) sacc[ct] = fp32x4{0,0,0,0};
  bf16x8 aF0 = *(const bf16x8*)&qs[wv * 16 + l15][quad * 8];
  bf16x8 aF1 = *(const bf16x8*)&qs[wv * 16 + l15][32 + quad * 8];
  #pragma unroll
  for (int ct = 0; ct < 16; ct++) {
    bf16x8 b0 = *(const bf16x8*)&klp[ct * 16 + l15][quad * 8];
    bf16x8 b1 = *(const bf16x8*)&klp[ct * 16 + l15][32 + quad * 8];
    sacc[ct] = __builtin_amdgcn_mfma_f32_16x16x32_bf16(aF0, b0, sacc[ct], 0, 0, 0);
    sacc[ct] = __builtin_amdgcn_mfma_f32_16x16x32_bf16(aF1, b1, sacc[ct], 0, 0, 0);
  }
  #pragma unroll
  for (int i = 0; i < 4; i++) {
    float m = -3.0e38f;
    #pragma unroll
    for (int ct = 0; ct < 16; ct++) m = fmaxf(m, sacc[ct][i]);
    #pragma unroll
    for (int o = 1; o < 16; o <<= 1) m = fmaxf(m, __shfl_xor(m, o));
    float s = 0.f;
    #pragma unroll
    for (int ct = 0; ct < 16; ct++) {
      float e = __expf(sacc[ct][i] - m);
      sacc[ct][i] = e;
      s += e;
    }
    #pragma unroll
    for (int o = 1; o < 16; o <<= 1) s += __shfl_xor(s, o);
    float inv = 1.f / s;
    #pragma unroll
    for (int ct = 0; ct < 16; ct++) sacc[ct][i] *= inv;
  }
  __syncthreads();
  u16* P = &klp[0][0];
  #pragma unroll
  for (int ct = 0; ct < 16; ct++)
    #pragma unroll
    for (int i = 0; i < 4; i++)
      P[(size_t)(wv * 16 + quad * 4 + i) * 264 + ct * 16 + l15] = f2bf(sacc[ct][i]);
  __syncthreads();

  fp32x4 oacc[4] = {fp32x4{0,0,0,0}, fp32x4{0,0,0,0}, fp32x4{0,0,0,0}, fp32x4{0,0,0,0}};
  #pragma unroll
  for (int ks = 0; ks < 8; ks++) {
    bf16x8 aP = *(const bf16x8*)&P[(size_t)(wv * 16 + l15) * 264 + ks * 32 + quad * 8];
    #pragma unroll
    for (int ct = 0; ct < 4; ct++) {
      bf16x8 bV = *(const bf16x8*)&kvs[ct * 16 + l15][ks * 32 + quad * 8];
      oacc[ct] = __builtin_amdgcn_mfma_f32_16x16x32_bf16(aP, bV, oacc[ct], 0, 0, 0);
    }
  }
  __syncthreads();
  float* osm = (float*)&klp[0][0];
  #pragma unroll
  for (int ct = 0; ct < 4; ct++)
    #pragma unroll
    for (int i = 0; i < 4; i++)
      osm[(size_t)(wv * 16 + quad * 4 + i) * 66 + ct * 16 + l15] = oacc[ct][i];
  float* vwin = (float*)&kvs[0][0];
  #pragma unroll
  for (int i = 0; i < 6; i++) {
    int r = i * 16 + (tid >> 4), c = (tid & 15) * 4;
    int g = n0 - 16 + r;
    float4 vv;
    if (g <= NPAD - 1) {
      bf16x4 bv = *(const bf16x4*)&vb[(size_t)g * DH + c];
      vv.x = bf2f((unsigned short)bv[0]); vv.y = bf2f((unsigned short)bv[1]);
      vv.z = bf2f((unsigned short)bv[2]); vv.w = bf2f((unsigned short)bv[3]);
    } else { vv.x = 0.f; vv.y = 0.f; vv.z = 0.f; vv.w = 0.f; }
    *(float4*)&vwin[r * 68 + c] = vv;
  }
  __syncthreads();
  {
    int c = tid & 63, rg = tid >> 6;
    float w[33];
    #pragma unroll
    for (int t = 0; t < 33; t++) w[t] = wsm[t];
    float a16[16];
    #pragma unroll
    for (int r = 0; r < 16; r++) a16[r] = osm[(size_t)(rg * 16 + r) * 66 + c];
    const float* vcol = &vwin[(size_t)(rg * 16) * 68 + c];
    #pragma unroll
    for (int j = 0; j < 48; j++) {
      float vj = vcol[(size_t)j * 68];
      #pragma unroll
      for (int r = 0; r < 16; r++) {
        int t = j - r;
        if (t >= 0 && t < 33) a16[r] += vj * w[t];
      }
    }
    int rowg = n0 + rg * 16;
    #pragma unroll
    for (int r = 0; r < 16; r++) {
      int n = rowg + r;
      if (n > NPAD - 1) continue;
      attn[((size_t)b * NTOK + (n - 255)) * EMBED + hh * DH + c] = f2bf(a16[r]);
    }
  }
}

// combine 7x7 + 5x5 + 3x3 + identity into one 7x7 depthwise kernel
__global__ void prep_wcomb_kernel(
    const float* __restrict__ pw7, const float* __restrict__ pw5,
    const float* __restrict__ pw3, const float* __restrict__ pb7,
    const float* __restrict__ pb5, const float* __restrict__ pb3,
    float* __restrict__ wcomb, float* __restrict__ biasc)
{
  int i = blockIdx.x * blockDim.x + threadIdx.x;
  if (i < EMBED * 49) {
    int c = i / 49, tap = i % 49;
    int ky = tap / 7, kx = tap % 7;
    float v = pw7[c * 49 + tap];
    if (ky >= 1 && ky <= 5 && kx >= 1 && kx <= 5) v += pw5[c * 25 + (ky - 1) * 5 + (kx - 1)];
    if (ky >= 2 && ky <= 4 && kx >= 2 && kx <= 4) v += pw3[c * 9 + (ky - 2) * 3 + (kx - 2)];
    if (ky == 3 && kx == 3) v += 1.f;
    wcomb[tap * EMBED + c] = v;
  }
  if (i < EMBED) biasc[i] = pb7[i] + pb5[i] + pb3[i];
}

// register-sliding-window depthwise conv:
// thread = one channel-pair (float2) x 16 x-positions x 1 row.
__global__ __launch_bounds__(256) void dwconv_kernel(
    const float* __restrict__ tmp, const float* __restrict__ wcomb,
    const float* __restrict__ biasc, float* __restrict__ h)
{
  int lane = threadIdx.x & 63;
  int xt = threadIdx.x >> 6;          // 0..3  (wave id -> wave-uniform branches)
  int cg = blockIdx.x;                 // 0..3 channel groups of 128
  int y  = blockIdx.y;                 // 0..63
  int b  = blockIdx.z;                 // 0..3
  int c  = cg * 128 + lane * 2;
  int x0 = xt * 16;
  const float* src = tmp + (size_t)b * N0 * EMBED + c;
  float2 bias = *(const float2*)&biasc[c];
  float2 acc[16];
  #pragma unroll
  for (int i = 0; i < 16; i++) acc[i] = bias;
  #pragma unroll
  for (int r = 0; r < 7; r++) {
    int row = y + r - 3;
    if (row < 0 || row >= 64) continue;           // block-uniform
    float2 w2[7];
    #pragma unroll
    for (int kx = 0; kx < 7; kx++)
      w2[kx] = *(const float2*)&wcomb[(size_t)(r * 7 + kx) * EMBED + c];
    float2 win[22];
    #pragma unroll
    for (int j = 0; j < 22; j++) {
      int xx = x0 + j - 3;
      if (xx >= 0 && xx < 64)                     // wave-uniform
        win[j] = *(const float2*)&src[((size_t)row * 64 + xx) * EMBED];
      else { win[j].x = 0.f; win[j].y = 0.f; }
    }
    #pragma unroll
    for (int kx = 0; kx < 7; kx++)
      #pragma unroll
      for (int i = 0; i < 16; i++) {
        acc[i].x += win[i + kx].x * w2[kx].x;
        acc[i].y += win[i + kx].y * w2[kx].y;
      }
  }
  float* dst = h + ((size_t)b * NTOK + 1 + (size_t)y * 64) * EMBED + c;
  #pragma unroll
  for (int i = 0; i < 16; i++)
    *(float2*)&dst[(size_t)(x0 + i) * EMBED] = acc[i];
}

__global__ __launch_bounds__(256) void final_kernel(
    const float* __restrict__ h, const float* __restrict__ g,
    const float* __restrict__ be, const float* __restrict__ W2,
    const float* __restrict__ b2, float* __restrict__ out)
{
  __shared__ float red[4];
  int b = blockIdx.x, tid = threadIdx.x;
  const float* x = h + (size_t)b * NTOK * EMBED;
  float v0 = x[tid], v1 = x[tid + 256];
  float mu = block_sum(v0 + v1, red) * (1.f / 512.f);
  float d0 = v0 - mu, d1 = v1 - mu;
  float var = block_sum(d0 * d0 + d1 * d1, red) * (1.f / 512.f);
  float inv = 1.f / sqrtf(var + 1e-5f);
  float xn0 = d0 * inv * g[tid] + be[tid];
  float xn1 = d1 * inv * g[tid + 256] + be[tid + 256];
  float l0 = block_sum(xn0 * W2[tid] + xn1 * W2[tid + 256], red);
  float l1 = block_sum(xn0 * W2[512 + tid] + xn1 * W2[512 + tid + 256], red);
  if (tid == 0) {
    l0 += b2[0]; l1 += b2[1];
    out[b * 2 + 0] = l0;
    out[b * 2 + 1] = l1;
    float mx = fmaxf(l0, l1);
    float e0 = expf(l0 - mx), e1 = expf(l1 - mx);
    float s = e0 + e1;
    out[8 + b * 2 + 0] = e0 / s;
    out[8 + b * 2 + 1] = e1 / s;
    out[16 + b] = (l1 > l0) ? 1.f : 0.f;
  }
}

// ------------------------------- host side -----------------------------------
extern "C" void kernel_launch(void* const* d_in, const int* in_sizes, int n_in,
                              void* d_out, int out_size, void* d_ws, size_t ws_size,
                              hipStream_t stream)
{
  const float* data = (const float*)d_in[0];
  const float* W1   = (const float*)d_in[1];
  const float* b1   = (const float*)d_in[2];
  const float* cls  = (const float*)d_in[3];
  const float* lng[2]  = {(const float*)d_in[4],  (const float*)d_in[10]};
  const float* lnb[2]  = {(const float*)d_in[5],  (const float*)d_in[11]};
  const float* Wqkv[2] = {(const float*)d_in[6],  (const float*)d_in[12]};
  const float* Wo[2]   = {(const float*)d_in[7],  (const float*)d_in[13]};
  const float* bo[2]   = {(const float*)d_in[8],  (const float*)d_in[14]};
  const float* resw[2] = {(const float*)d_in[9],  (const float*)d_in[15]};
  const float* pw7 = (const float*)d_in[16];
  const float* pb7 = (const float*)d_in[17];
  const float* pw5 = (const float*)d_in[18];
  const float* pb5 = (const float*)d_in[19];
  const float* pw3 = (const float*)d_in[20];
  const float* pb3 = (const float*)d_in[21];
  const float* lnfg = (const float*)d_in[22];
  const float* lnfb = (const float*)d_in[23];
  const float* W2  = (const float*)d_in[24];
  const float* b2  = (const float*)d_in[25];

  float* ws = (float*)d_ws;
  size_t off = 0;
  auto alloc = [&](size_t n) { float* p = ws + off; off += n; return p; };
  float* hbuf   = alloc((size_t)BATCH * NTOK * EMBED);          // fp32
  float* xpadf  = alloc((size_t)BATCH * NPAD * EMBED);          // bf16 (half) + attn reuse
  float* qbuff  = alloc((size_t)BH * NPAD * DH);                // q bf16 / databf / conv tmp fp32
  float* kbuff  = alloc((size_t)BH * NPAD * DH);                // k bf16 (half) + databf tail
  float* vbuff  = alloc((size_t)BH * NPAD * DH);                // v bf16 (half) + W1bf tail
  float* qland  = alloc((size_t)BH * MM * DH);
  float* kland  = alloc((size_t)BH * MM * DH);
  float* a2f    = alloc((size_t)BH * MM * MM / 2);              // bf16
  float* zaRf   = alloc((size_t)BH * MM * MM / 2);
  float* zaCf   = alloc((size_t)BH * MM * MM / 2);
  float* zbRf   = alloc((size_t)BH * MM * MM / 2);
  float* zbCf   = alloc((size_t)BH * MM * MM / 2);
  float* xzRf   = alloc((size_t)BH * MM * MM / 2);
  float* xzCf   = alloc((size_t)BH * MM * MM / 2);
  float* t1Cf   = alloc((size_t)BH * MM * MM / 2);
  float* t2Cf   = alloc((size_t)BH * MM * MM / 2);
  float* kvTf   = alloc((size_t)BH * MM * DH / 2);
  float* kv2Tf  = alloc((size_t)BH * MM * DH / 2);
  float* wqkvbf = alloc((size_t)2 * 3 * EMBED * EMBED / 2);     // bf16 x2 layers
  float* wobf   = alloc((size_t)2 * EMBED * EMBED / 2);
  float* wcomb  = alloc(49 * EMBED);
  float* biasc  = alloc(EMBED);
  float* denoms = alloc(64);
  float* mpart  = alloc((size_t)NSEG * BH * MM);
  float* lpart  = alloc((size_t)NSEG * BH * MM);

  u16* xpadB = (u16*)xpadf;
  u16* qB = (u16*)qbuff;
  u16* kB = (u16*)kbuff;
  u16* vB = (u16*)vbuff;
  u16* a2B = (u16*)a2f;
  u16* zaR = (u16*)zaRf; u16* zaC = (u16*)zaCf;
  u16* xzR = (u16*)xzRf;
  u16* kvT = (u16*)kvTf; u16* kv2T = (u16*)kv2Tf;
  u16* attnB = xpadB;
  u16* OpartB = zaR;                       // overlay: free until pinv_chain
  u16* databf = (u16*)qbuff;               // overlay: consumed by input GEMM only
  u16* W1bf = (u16*)vbuff;                 // overlay: consumed by input GEMM only
  u16* WqkvB[2] = {(u16*)wqkvbf, (u16*)wqkvbf + (size_t)3 * EMBED * EMBED};
  u16* WoB[2]   = {(u16*)wobf,   (u16*)wobf + (size_t)EMBED * EMBED};
  float* convtmp = qbuff;

  // ---- one-time bf16 conversions ----
  int ndata = BATCH * N0 * CIN;
  f2bf_kernel<<<dim3((ndata / 8 + 255) / 256), 256, 0, stream>>>(data, databf, ndata);
  f2bf_kernel<<<dim3((EMBED * CIN / 8 + 255) / 256), 256, 0, stream>>>(W1, W1bf, EMBED * CIN);
  for (int l = 0; l < 2; l++) {
    f2bf_kernel<<<dim3((3 * EMBED * EMBED / 8 + 255) / 256), 256, 0, stream>>>(Wqkv[l], WqkvB[l], 3 * EMBED * EMBED);
    f2bf_kernel<<<dim3((EMBED * EMBED / 8 + 255) / 256), 256, 0, stream>>>(Wo[l], WoB[l], EMBED * EMBED);
  }

  gemm_abt<<<dim3(EMBED / 128, (BATCH * N0) / 64), 256, 0, stream>>>(
      databf, W1bf, BATCH * N0, EMBED, CIN, b1, hbuf, nullptr, nullptr, nullptr, nullptr, 0);
  cls_kernel<<<dim3((BATCH * EMBED + 255) / 256), 256, 0, stream>>>(cls, hbuf);

  for (int layer = 0; layer < 2; layer++) {
    ln_pad_kernel<<<dim3(BATCH * NTOK), 256, 0, stream>>>(hbuf, lng[layer], lnb[layer], xpadB);
    zero_pad_kernel<<<dim3((BATCH * 255 * EMBED + 255) / 256), 256, 0, stream>>>(xpadB);
    gemm_abt<<<dim3((3 * EMBED) / 128, (BATCH * NPAD) / 64), 256, 0, stream>>>(
        xpadB, WqkvB[layer], BATCH * NPAD, 3 * EMBED, EMBED, nullptr,
        nullptr, nullptr, qB, kB, vB, 1);
    landmarks_kernel<<<dim3(MM / 4, BH), 256, 0, stream>>>(qB, kB, qland, kland);
    s2_softmax_kernel<<<dim3(MM, BH), 256, 0, stream>>>(qland, kland, a2B);
    init_denom_kernel<<<1, 64, 0, stream>>>(denoms);
    denom_kernel<<<dim3(BH), 256, 0, stream>>>(a2B, denoms);

    // a3@v before pinv so Opart can overlay the pinv scratch
    a3v_part_mfma<<<dim3(4 * NSEG, BH), 256, 0, stream>>>(
        qland, kB, vB, OpartB, mpart, lpart);
    a3v_merge_kernel<<<dim3(MM / 64, BH), 256, 0, stream>>>(OpartB, mpart, lpart, kvT);

    // persistent per-bh pinv chain, B operand LDS-resident across all steps
    pinv_chain<<<dim3(BH), 1024, 0, stream>>>(
        a2B, denoms, zaR, zaC, xzR, kvT, kv2T);

    attn1_mfma<<<dim3((NTOK + 63) / 64, BH), 256, 0, stream>>>(
        qB, kland, kv2T, vB, resw[layer], attnB);
    gemm_abt<<<dim3(EMBED / 128, (BATCH * NTOK + 63) / 64), 256, 0, stream>>>(
        attnB, WoB[layer], BATCH * NTOK, EMBED, EMBED, bo[layer], hbuf,
        (layer == 0) ? convtmp : nullptr, nullptr, nullptr, nullptr,
        (layer == 0) ? 3 : 2);

    if (layer == 0) {
      prep_wcomb_kernel<<<dim3((EMBED * 49 + 255) / 256), 256, 0, stream>>>(
          pw7, pw5, pw3, pb7, pb5, pb3, wcomb, biasc);
      dwconv_kernel<<<dim3(4, 64, BATCH), 256, 0, stream>>>(
          convtmp, wcomb, biasc, hbuf);
    }
  }

  final_kernel<<<dim3(BATCH), 256, 0, stream>>>(hbuf, lnfg, lnfb, W2, b2, (float*)d_out);
}

// Round 9
// 1397.022 us; speedup vs baseline: 2.1231x; 2.1231x over previous
//
#include <hip/hip_runtime.h>
#include <math.h>

#define EMBED 512
#define HEADS 8
#define DH 64
#define MM 256
#define LSEG 17
#define NPAD 4352
#define NTOK 4097
#define N0 4096
#define BATCH 4
#define CIN 1536
#define QSCALE 0.125f
#define BH 32   // BATCH*HEADS
#define NSEG 17 // key segments of 256 for a3v

typedef float fp32x4 __attribute__((ext_vector_type(4)));
typedef short bf16x8 __attribute__((ext_vector_type(8)));
typedef short bf16x4 __attribute__((ext_vector_type(4)));
typedef unsigned short u16;

__device__ __forceinline__ unsigned short f2bf(float f) {
  unsigned int u = __float_as_uint(f);
  u += 0x7fffu + ((u >> 16) & 1u);
  return (unsigned short)(u >> 16);
}
__device__ __forceinline__ float bf2f(unsigned short u) {
  return __uint_as_float((unsigned)u << 16);
}

// ---------------- block reduction helpers (blockDim.x == 256) ----------------
__device__ __forceinline__ float block_sum(float v, float* red) {
  #pragma unroll
  for (int o = 1; o < 64; o <<= 1) v += __shfl_xor(v, o);
  int lane = threadIdx.x & 63, wid = threadIdx.x >> 6;
  if (lane == 0) red[wid] = v;
  __syncthreads();
  float r = red[0] + red[1] + red[2] + red[3];
  __syncthreads();
  return r;
}
__device__ __forceinline__ float block_max(float v, float* red) {
  #pragma unroll
  for (int o = 1; o < 64; o <<= 1) v = fmaxf(v, __shfl_xor(v, o));
  int lane = threadIdx.x & 63, wid = threadIdx.x >> 6;
  if (lane == 0) red[wid] = v;
  __syncthreads();
  float r = fmaxf(fmaxf(red[0], red[1]), fmaxf(red[2], red[3]));
  __syncthreads();
  return r;
}

// fp32 -> bf16 convert (n multiple of 8)
__global__ void f2bf_kernel(const float* __restrict__ in, u16* __restrict__ out, int n) {
  int t = (blockIdx.x * 256 + threadIdx.x) * 8;
  if (t >= n) return;
  float4 a = *(const float4*)&in[t];
  float4 b = *(const float4*)&in[t + 4];
  bf16x8 pk;
  pk[0]=(short)f2bf(a.x); pk[1]=(short)f2bf(a.y); pk[2]=(short)f2bf(a.z); pk[3]=(short)f2bf(a.w);
  pk[4]=(short)f2bf(b.x); pk[5]=(short)f2bf(b.y); pk[6]=(short)f2bf(b.z); pk[7]=(short)f2bf(b.w);
  *(bf16x8*)&out[t] = pk;
}

// 4 weight tensors in one launch (grid.y selects tensor)
__global__ void f2bfw_kernel(
    const float* __restrict__ s0, const float* __restrict__ s1,
    const float* __restrict__ s2, const float* __restrict__ s3,
    u16* __restrict__ d0, u16* __restrict__ d1,
    u16* __restrict__ d2, u16* __restrict__ d3,
    int n0, int n1, int n2, int n3)
{
  int y = blockIdx.y;
  const float* s = (y == 0) ? s0 : (y == 1) ? s1 : (y == 2) ? s2 : s3;
  u16* d = (y == 0) ? d0 : (y == 1) ? d1 : (y == 2) ? d2 : d3;
  int n = (y == 0) ? n0 : (y == 1) ? n1 : (y == 2) ? n2 : n3;
  int t = (blockIdx.x * 256 + threadIdx.x) * 8;
  if (t >= n) return;
  float4 a = *(const float4*)&s[t];
  float4 b = *(const float4*)&s[t + 4];
  bf16x8 pk;
  pk[0]=(short)f2bf(a.x); pk[1]=(short)f2bf(a.y); pk[2]=(short)f2bf(a.z); pk[3]=(short)f2bf(a.w);
  pk[4]=(short)f2bf(b.x); pk[5]=(short)f2bf(b.y); pk[6]=(short)f2bf(b.z); pk[7]=(short)f2bf(b.w);
  *(bf16x8*)&d[t] = pk;
}

// ------- bf16-MFMA GEMM  C = A(M,K)bf16 @ W(N,K)bf16^T,  64x128 tile --------
// mode 0: relu(acc+bias) -> hbuf fp32 scatter
// mode 1: qkv scatter -> q/k/v bf16
// mode 2: fout += acc+bias (residual)
// mode 3: mode2 + copy full rows (minus cls) to fout2 (conv tmp fp32)
__global__ __launch_bounds__(256) void gemm_abt(
    const u16* __restrict__ A, const u16* __restrict__ W,
    int Mrows, int Ncols, int K, const float* __restrict__ bias,
    float* __restrict__ fout, float* __restrict__ fout2,
    u16* __restrict__ uo0, u16* __restrict__ uo1, u16* __restrict__ uo2,
    int mode)
{
  __shared__ u16 As[64][40];
  __shared__ u16 Ws[128][40];
  int tid = threadIdx.x;
  int lane = tid & 63;
  int wv = tid >> 6;
  int rowBase = blockIdx.y * 64, colBase = blockIdx.x * 128;
  int quad = lane >> 4;
  int l15 = lane & 15;
  int sr = tid >> 2;
  int skc = (tid & 3) * 8;

  fp32x4 acc[8];
  #pragma unroll
  for (int i = 0; i < 8; i++) acc[i] = fp32x4{0,0,0,0};

  for (int kb = 0; kb < K; kb += 32) {
    __syncthreads();
    {
      int grow = rowBase + sr;
      bf16x8 av;
      if (grow < Mrows) av = *(const bf16x8*)&A[(size_t)grow * K + kb + skc];
      else { bf16x8 z = {0,0,0,0,0,0,0,0}; av = z; }
      *(bf16x8*)&As[sr][skc] = av;
    }
    #pragma unroll
    for (int h = 0; h < 2; h++) {
      int r = sr + h * 64;
      *(bf16x8*)&Ws[r][skc] =
          *(const bf16x8*)&W[(size_t)(colBase + r) * K + kb + skc];
    }
    __syncthreads();
    bf16x8 aF = *(const bf16x8*)&As[wv * 16 + l15][quad * 8];
    #pragma unroll
    for (int ct = 0; ct < 8; ct++) {
      bf16x8 bF = *(const bf16x8*)&Ws[ct * 16 + l15][quad * 8];
      acc[ct] = __builtin_amdgcn_mfma_f32_16x16x32_bf16(aF, bF, acc[ct], 0, 0, 0);
    }
  }

  #pragma unroll
  for (int ct = 0; ct < 8; ct++) {
    int col = colBase + ct * 16 + l15;
    #pragma unroll
    for (int i = 0; i < 4; i++) {
      int row = rowBase + wv * 16 + quad * 4 + i;
      if (row >= Mrows) continue;
      float v = acc[ct][i];
      if (mode == 0) {
        v += bias[col];
        v = fmaxf(v, 0.f);
        int b = row / N0, n = row % N0;
        fout[((size_t)b * NTOK + 1 + n) * EMBED + col] = v;
      } else if (mode == 1) {
        int b = row / NPAD, n = row % NPAD;
        int sec = col / EMBED;
        int hh = (col % EMBED) / DH;
        int d = col & 63;
        u16* dst = (sec == 0) ? uo0 : ((sec == 1) ? uo1 : uo2);
        if (sec == 0) v *= QSCALE;
        dst[(((size_t)b * HEADS + hh) * NPAD + n) * DH + d] = f2bf(v);
      } else if (mode == 2) {
        v += bias[col];
        fout[(size_t)row * EMBED + col] += v;
      } else {
        v += bias[col];
        float full = fout[(size_t)row * EMBED + col] + v;
        fout[(size_t)row * EMBED + col] = full;
        int b = row / NTOK, t = row % NTOK;
        if (t > 0) fout2[((size_t)b * N0 + (t - 1)) * EMBED + col] = full;
      }
    }
  }
}

// ---- pinv GEMM body (full-K single-stage, 64x64 tile per block) -------------
// C = gamma*(sgn*(A@B) + beta*A + delta*D). Bc is B^T row-major. A, D row-major.
// All batch offsets pre-applied by caller. ONE barrier per GEMM.
__device__ __forceinline__ void pinv_body(
    u16 As[64][264], u16 Bs[64][264],
    const u16* Ab, const u16* Bb, const u16* Db,
    u16* Cr, u16* Cc, int Nsize,
    float beta, float sgn, float gamma, float delta,
    int rowBase, int colBase)
{
  int tid = threadIdx.x;
  int lane = tid & 63, wv = tid >> 6, quad = lane >> 4, l15 = lane & 15;
  int sr = tid >> 2, skc = (tid & 3) * 8;

  #pragma unroll
  for (int kb = 0; kb < 8; kb++) {
    *(bf16x8*)&As[sr][kb * 32 + skc] =
        *(const bf16x8*)&Ab[(size_t)(rowBase + sr) * MM + kb * 32 + skc];
    *(bf16x8*)&Bs[sr][kb * 32 + skc] =
        *(const bf16x8*)&Bb[(size_t)(colBase + sr) * MM + kb * 32 + skc];
  }
  __syncthreads();

  fp32x4 acc[4] = {fp32x4{0,0,0,0}, fp32x4{0,0,0,0}, fp32x4{0,0,0,0}, fp32x4{0,0,0,0}};
  #pragma unroll
  for (int kb = 0; kb < 8; kb++) {
    bf16x8 aF = *(const bf16x8*)&As[wv * 16 + l15][kb * 32 + quad * 8];
    #pragma unroll
    for (int ct = 0; ct < 4; ct++) {
      bf16x8 bF = *(const bf16x8*)&Bs[ct * 16 + l15][kb * 32 + quad * 8];
      acc[ct] = __builtin_amdgcn_mfma_f32_16x16x32_bf16(aF, bF, acc[ct], 0, 0, 0);
    }
  }

  #pragma unroll
  for (int ct = 0; ct < 4; ct++) {
    int col = colBase + ct * 16 + l15;
    #pragma unroll
    for (int i = 0; i < 4; i++) {
      int row = rowBase + wv * 16 + quad * 4 + i;
      float v = sgn * acc[ct][i];
      if (beta != 0.f) v += beta * bf2f(Ab[(size_t)row * MM + col]);
      if (delta != 0.f) v += delta * bf2f(Db[(size_t)row * MM + col]);
      v *= gamma;
      u16 o = f2bf(v);
      if (Cr) Cr[(size_t)row * Nsize + col] = o;
      if (Cc) Cc[(size_t)col * MM + row] = o;
    }
  }
}

// generic step (used for y = a2@z and the final z@kv)
__global__ __launch_bounds__(256) void gemm_nn2(
    const u16* __restrict__ A, const u16* __restrict__ Bc,
    u16* __restrict__ Cr, u16* __restrict__ Cc,
    int Nsize, float beta, float sgn, float gamma)
{
  __shared__ u16 As[64][264];
  __shared__ u16 Bs[64][264];
  int batch = blockIdx.z;
  size_t mo = (size_t)batch * MM * MM;
  size_t no = (size_t)batch * MM * Nsize;
  pinv_body(As, Bs, A + mo, Bc + no, nullptr,
            Cr ? Cr + no : nullptr, Cc ? Cc + no : nullptr,
            Nsize, beta, sgn, gamma, 0.f, blockIdx.y * 64, blockIdx.x * 64);
}

// merged {u = 7y - y@y  -> uC (col)} and {w = z@y -> wR (row)} in one launch.
// grid (4, 8, BH): blockIdx.y<4 -> u task, else w task. Both consume Bc = yC.
__global__ __launch_bounds__(256) void gemm_pair(
    const u16* __restrict__ yR, const u16* __restrict__ zR,
    const u16* __restrict__ yC, u16* __restrict__ uC, u16* __restrict__ wR)
{
  __shared__ u16 As[64][264];
  __shared__ u16 Bs[64][264];
  int batch = blockIdx.z;
  size_t mo = (size_t)batch * MM * MM;
  int task = blockIdx.y >> 2, by = blockIdx.y & 3;
  if (task == 0)
    pinv_body(As, Bs, yR + mo, yC + mo, nullptr, nullptr, uC + mo,
              MM, 7.f, -1.f, 1.f, 0.f, by * 64, blockIdx.x * 64);
  else
    pinv_body(As, Bs, zR + mo, yC + mo, nullptr, wR + mo, nullptr,
              MM, 0.f, 1.f, 1.f, 0.f, by * 64, blockIdx.x * 64);
}

// z' = 0.25*(w@u - 15w + 13z)  (algebraically == 0.25*(13z - z@t2))
__global__ __launch_bounds__(256) void gemm_zstep(
    const u16* __restrict__ wR, const u16* __restrict__ uC,
    const u16* __restrict__ zin, u16* __restrict__ zoutR, u16* __restrict__ zoutC)
{
  __shared__ u16 As[64][264];
  __shared__ u16 Bs[64][264];
  int batch = blockIdx.z;
  size_t mo = (size_t)batch * MM * MM;
  pinv_body(As, Bs, wR + mo, uC + mo, zin + mo, zoutR + mo, zoutC + mo,
            MM, -15.f, 1.f, 0.25f, 13.f, blockIdx.y * 64, blockIdx.x * 64);
}

// ---------------- small utility kernels ----------------
__global__ void cls_kernel(const float* __restrict__ cls, float* __restrict__ h) {
  int t = blockIdx.x * blockDim.x + threadIdx.x;
  if (t >= BATCH * EMBED) return;
  int b = t / EMBED, c = t % EMBED;
  h[(size_t)b * NTOK * EMBED + c] = cls[c];
}

// LN -> bf16 padded; pad rows (j<255) zeroed in the same launch
__global__ __launch_bounds__(256) void ln_pad_kernel(
    const float* __restrict__ h, const float* __restrict__ g,
    const float* __restrict__ be, u16* __restrict__ xpad)
{
  __shared__ float red[4];
  int row = blockIdx.x;
  int b = row / NPAD, j = row % NPAD;
  int tid = threadIdx.x;
  if (j < 255) {                       // block-uniform branch: zero the pad row
    ((float*)(xpad + (size_t)row * EMBED))[tid] = 0.f;
    return;
  }
  j -= 255;
  const float* x = h + ((size_t)b * NTOK + j) * EMBED;
  float v0 = x[tid], v1 = x[tid + 256];
  float mu = block_sum(v0 + v1, red) * (1.f / 512.f);
  float d0 = v0 - mu, d1 = v1 - mu;
  float var = block_sum(d0 * d0 + d1 * d1, red) * (1.f / 512.f);
  float inv = 1.f / sqrtf(var + 1e-5f);
  u16* o = xpad + ((size_t)b * NPAD + 255 + j) * EMBED;
  o[tid]       = f2bf(d0 * inv * g[tid]       + be[tid]);
  o[tid + 256] = f2bf(d1 * inv * g[tid + 256] + be[tid + 256]);
}

__global__ __launch_bounds__(256) void landmarks_kernel(
    const u16* __restrict__ q, const u16* __restrict__ k,
    float* __restrict__ qland, float* __restrict__ kland)
{
  int bh = blockIdx.y;
  int m = blockIdx.x * 4 + (threadIdx.x >> 6);
  int d = threadIdx.x & 63;
  const u16* qb = q + (size_t)bh * NPAD * DH;
  const u16* kb = k + (size_t)bh * NPAD * DH;
  float sq = 0.f, sk = 0.f;
  int base = m * LSEG;
  #pragma unroll
  for (int t = 0; t < LSEG; t++) {
    sq += bf2f(qb[(size_t)(base + t) * DH + d]);
    sk += bf2f(kb[(size_t)(base + t) * DH + d]);
  }
  qland[((size_t)bh * MM + m) * DH + d] = sq * (1.f / LSEG);
  kland[((size_t)bh * MM + m) * DH + d] = sk * (1.f / LSEG);
}

__global__ __launch_bounds__(256) void s2_softmax_kernel(
    const float* __restrict__ qland, const float* __restrict__ kland,
    u16* __restrict__ a2)
{
  __shared__ float qrow[64];
  __shared__ float red[4];
  int bh = blockIdx.y, m = blockIdx.x, tid = threadIdx.x;
  if (tid < 64) qrow[tid] = qland[((size_t)bh * MM + m) * DH + tid];
  __syncthreads();
  const float* kb = kland + (size_t)bh * MM * DH + (size_t)tid * DH;
  float s = 0.f;
  #pragma unroll 16
  for (int d = 0; d < 64; d++) s += qrow[d] * kb[d];
  float mx = block_max(s, red);
  float e = __expf(s - mx);
  float tot = block_sum(e, red);
  a2[((size_t)bh * MM + m) * MM + tid] = f2bf(e / tot);
}

__global__ void init_denom_kernel(float* __restrict__ denoms) {
  if (threadIdx.x < 4) denoms[threadIdx.x] = 0.f;   // both layers' slots
}

__global__ __launch_bounds__(256) void denom_kernel(
    const u16* __restrict__ a2, float* __restrict__ denoms)
{
  __shared__ float red[4];
  int bh = blockIdx.x, tid = threadIdx.x;
  const u16* A = a2 + (size_t)bh * MM * MM;
  float rs = 0.f, cs = 0.f;
  for (int j = 0; j < MM; j++) rs += bf2f(A[(size_t)tid * MM + j]);
  for (int i = 0; i < MM; i++) cs += bf2f(A[(size_t)i * MM + tid]);
  float mr = block_max(rs, red);
  float mc = block_max(cs, red);
  if (tid == 0) {
    atomicMax((int*)&denoms[0], __float_as_int(mr));
    atomicMax((int*)&denoms[1], __float_as_int(mc));
  }
}

// z0: zr = a2^T/denom (row-major), zc = a2/denom (= z^T row-major)
__global__ __launch_bounds__(256) void z0_trans_kernel(
    const u16* __restrict__ a2, const float* __restrict__ denoms,
    u16* __restrict__ zr, u16* __restrict__ zc)
{
  __shared__ u16 tile[64][72];
  int bh = blockIdx.z, i0 = blockIdx.y * 64, j0 = blockIdx.x * 64;
  int tid = threadIdx.x;
  float inv = 1.f / (denoms[0] * denoms[1]);
  const u16* Ab = a2 + (size_t)bh * MM * MM;
  #pragma unroll
  for (int it = 0; it < 4; it++) {
    int idx = it * 1024 + tid * 4;
    int r = idx >> 6, c = idx & 63;
    bf16x4 v = *(const bf16x4*)&Ab[(size_t)(i0 + r) * MM + j0 + c];
    u16 o[4];
    #pragma unroll
    for (int j = 0; j < 4; j++) o[j] = f2bf(bf2f((unsigned short)v[j]) * inv);
    *(bf16x4*)&zc[(size_t)bh * MM * MM + (size_t)(i0 + r) * MM + j0 + c] = *(bf16x4*)o;
    #pragma unroll
    for (int j = 0; j < 4; j++) tile[c + j][r] = o[j];
  }
  __syncthreads();
  #pragma unroll
  for (int it = 0; it < 4; it++) {
    int idx = it * 1024 + tid * 4;
    int r = idx >> 6, c = idx & 63;
    u16 o[4] = {tile[r][c], tile[r][c + 1], tile[r][c + 2], tile[r][c + 3]};
    *(bf16x4*)&zr[(size_t)bh * MM * MM + (size_t)(j0 + r) * MM + i0 + c] = *(bf16x4*)o;
  }
}

// ---- MFMA a3@v partial flash: block = 64 landmarks x 256-key segment --------
__global__ __launch_bounds__(256) void a3v_part_mfma(
    const float* __restrict__ qland, const u16* __restrict__ k,
    const u16* __restrict__ v, u16* __restrict__ Opart,
    float* __restrict__ mpart, float* __restrict__ lpart)
{
  __shared__ __align__(16) u16 qs[64][40];
  __shared__ __align__(16) u16 ks[256][72];   // reused for P[64][264]
  __shared__ __align__(16) u16 vt[64][72];
  int tid = threadIdx.x;
  int lane = tid & 63, wv = tid >> 6, quad = lane >> 4, l15 = lane & 15;
  int bh = blockIdx.y;
  int ltile = blockIdx.x & 3;
  int seg = blockIdx.x >> 2;
  int l0 = ltile * 64;
  int key0 = seg * 256;
  const float* qb = qland + (size_t)bh * MM * DH;
  const u16* kb = k + (size_t)bh * NPAD * DH;
  const u16* vb = v + (size_t)bh * NPAD * DH;

  {
    int sr = tid >> 2, dc = (tid & 3) * 16;
    const float4* p = (const float4*)&qb[(size_t)(l0 + sr) * DH + dc];
    float4 v0 = p[0], v1 = p[1], v2 = p[2], v3 = p[3];
    float va[16] = {v0.x,v0.y,v0.z,v0.w, v1.x,v1.y,v1.z,v1.w,
                    v2.x,v2.y,v2.z,v2.w, v3.x,v3.y,v3.z,v3.w};
    bf16x8 p0, p1;
    #pragma unroll
    for (int j = 0; j < 8; j++) { p0[j] = (short)f2bf(va[j]); p1[j] = (short)f2bf(va[8 + j]); }
    *(bf16x8*)&qs[sr][dc] = p0;
    *(bf16x8*)&qs[sr][dc + 8] = p1;
  }
  #pragma unroll
  for (int i = 0; i < 16; i++) {
    int idx = i * 1024 + tid * 4;
    int r = idx >> 6, c = idx & 63;
    *(bf16x4*)&ks[r][c] = *(const bf16x4*)&kb[(size_t)(key0 + r) * DH + c];
  }
  __syncthreads();

  fp32x4 sacc[16];
  #pragma unroll
  for (int ct = 0; ct < 16; ct++) sacc[ct] = fp32x4{0,0,0,0};
  bf16x8 aF0 = *(const bf16x8*)&qs[wv * 16 + l15][quad * 8];
  bf16x8 aF1 = *(const bf16x8*)&qs[wv * 16 + l15][32 + quad * 8];
  #pragma unroll
  for (int ct = 0; ct < 16; ct++) {
    bf16x8 b0 = *(const bf16x8*)&ks[ct * 16 + l15][quad * 8];
    bf16x8 b1 = *(const bf16x8*)&ks[ct * 16 + l15][32 + quad * 8];
    sacc[ct] = __builtin_amdgcn_mfma_f32_16x16x32_bf16(aF0, b0, sacc[ct], 0, 0, 0);
    sacc[ct] = __builtin_amdgcn_mfma_f32_16x16x32_bf16(aF1, b1, sacc[ct], 0, 0, 0);
  }

  float mrow[4], lrow[4];
  #pragma unroll
  for (int i = 0; i < 4; i++) {
    float m = -3.0e38f;
    #pragma unroll
    for (int ct = 0; ct < 16; ct++) m = fmaxf(m, sacc[ct][i]);
    #pragma unroll
    for (int o = 1; o < 16; o <<= 1) m = fmaxf(m, __shfl_xor(m, o));
    float s = 0.f;
    #pragma unroll
    for (int ct = 0; ct < 16; ct++) {
      float e = __expf(sacc[ct][i] - m);
      sacc[ct][i] = e;
      s += e;
    }
    #pragma unroll
    for (int o = 1; o < 16; o <<= 1) s += __shfl_xor(s, o);
    mrow[i] = m;
    lrow[i] = s;
  }
  __syncthreads();
  u16* P = &ks[0][0];
  #pragma unroll
  for (int ct = 0; ct < 16; ct++)
    #pragma unroll
    for (int i = 0; i < 4; i++)
      P[(size_t)(wv * 16 + quad * 4 + i) * 264 + ct * 16 + l15] = f2bf(sacc[ct][i]);
  __syncthreads();

  fp32x4 oacc[4] = {fp32x4{0,0,0,0}, fp32x4{0,0,0,0}, fp32x4{0,0,0,0}, fp32x4{0,0,0,0}};
  int dh = tid & 63, kgrp = tid >> 6;
  for (int ch = 0; ch < 4; ch++) {
    if (ch) __syncthreads();
    {
      int kbase = kgrp * 16;
      #pragma unroll
      for (int g = 0; g < 4; g++) {
        u16 pk[4];
        #pragma unroll
        for (int r = 0; r < 4; r++)
          pk[r] = vb[(size_t)(key0 + ch * 64 + kbase + g * 4 + r) * DH + dh];
        *(bf16x4*)&vt[dh][kbase + g * 4] = *(bf16x4*)pk;
      }
    }
    __syncthreads();
    #pragma unroll
    for (int ks2 = 0; ks2 < 2; ks2++) {
      bf16x8 aP = *(const bf16x8*)&P[(size_t)(wv * 16 + l15) * 264 + ch * 64 + ks2 * 32 + quad * 8];
      #pragma unroll
      for (int ct = 0; ct < 4; ct++) {
        bf16x8 bV = *(const bf16x8*)&vt[ct * 16 + l15][ks2 * 32 + quad * 8];
        oacc[ct] = __builtin_amdgcn_mfma_f32_16x16x32_bf16(aP, bV, oacc[ct], 0, 0, 0);
      }
    }
  }

  size_t base = ((size_t)seg * BH + bh) * MM + l0;
  #pragma unroll
  for (int ct = 0; ct < 4; ct++)
    #pragma unroll
    for (int i = 0; i < 4; i++) {
      int row = wv * 16 + quad * 4 + i;
      Opart[(base + row) * DH + ct * 16 + l15] = f2bf(oacc[ct][i]);
    }
  if (l15 == 0) {
    #pragma unroll
    for (int i = 0; i < 4; i++) {
      int row = wv * 16 + quad * 4 + i;
      mpart[base + row] = mrow[i];
      lpart[base + row] = lrow[i];
    }
  }
}

// merge partials -> kv^T (col-major for the z@kv GEMM's B operand)
__global__ __launch_bounds__(256) void a3v_merge_kernel(
    const u16* __restrict__ Opart, const float* __restrict__ mpart,
    const float* __restrict__ lpart, u16* __restrict__ kvT)
{
  int bh = blockIdx.y;
  int lbase = blockIdx.x * 64;
  int d = threadIdx.x & 63, lsub = threadIdx.x >> 6;
  for (int li = lsub; li < 64; li += 4) {
    int lm = lbase + li;
    float M = -3.0e38f;
    #pragma unroll
    for (int s = 0; s < NSEG; s++)
      M = fmaxf(M, mpart[((size_t)s * BH + bh) * MM + lm]);
    float L = 0.f, O = 0.f;
    #pragma unroll
    for (int s = 0; s < NSEG; s++) {
      size_t idx = ((size_t)s * BH + bh) * MM + lm;
      float w = __expf(mpart[idx] - M);
      L += lpart[idx] * w;
      O += bf2f(Opart[idx * DH + d]) * w;
    }
    kvT[((size_t)bh * DH + d) * MM + lm] = f2bf(O / L);
  }
}

// ---- MFMA fused a1-softmax @ kv2T + res-conv(33): 64 rows/block -------------
__global__ __launch_bounds__(256, 2) void attn1_mfma(
    const u16* __restrict__ q, const float* __restrict__ kland,
    const u16* __restrict__ kv2T, const u16* __restrict__ v,
    const float* __restrict__ resw, u16* __restrict__ attn)
{
  __shared__ __align__(16) u16 qs[64][40];
  __shared__ __align__(16) u16 klp[256][72];   // reused: P[64][264], then osm fp32[64][66]
  __shared__ __align__(16) u16 kvs[64][264];   // reused: vwin fp32[96][68]
  __shared__ float wsm[33];
  int tid = threadIdx.x;
  int lane = tid & 63, wv = tid >> 6, quad = lane >> 4, l15 = lane & 15;
  int bh = blockIdx.y, b = bh >> 3, hh = bh & 7;
  int n0 = 255 + blockIdx.x * 64;
  const u16* qb  = q + (size_t)bh * NPAD * DH;
  const float* klb = kland + (size_t)bh * MM * DH;
  const u16* kvb = kv2T + (size_t)bh * DH * MM;
  const u16* vb  = v + (size_t)bh * NPAD * DH;
  if (tid < 33) wsm[tid] = resw[hh * 33 + tid];

  {
    int sr = tid >> 2, dc = (tid & 3) * 16;
    int g = n0 + sr; if (g > NPAD - 1) g = NPAD - 1;
    *(bf16x8*)&qs[sr][dc]     = *(const bf16x8*)&qb[(size_t)g * DH + dc];
    *(bf16x8*)&qs[sr][dc + 8] = *(const bf16x8*)&qb[(size_t)g * DH + dc + 8];
  }
  #pragma unroll
  for (int i = 0; i < 16; i++) {
    int idx = i * 1024 + tid * 4;
    int r = idx >> 6, c = idx & 63;
    float4 vv = *(const float4*)&klb[(size_t)r * DH + c];
    bf16x4 pk = { (short)f2bf(vv.x), (short)f2bf(vv.y), (short)f2bf(vv.z), (short)f2bf(vv.w) };
    *(bf16x4*)&klp[r][c] = pk;
  }
  #pragma unroll
  for (int i = 0; i < 8; i++) {
    int idx = i * 2048 + tid * 8;
    int r = idx >> 8, c = idx & 255;
    *(bf16x8*)&kvs[r][c] = *(const bf16x8*)&kvb[(size_t)r * MM + c];
  }
  __syncthreads();

  fp32x4 sacc[16];
  #pragma unroll
  for (int ct = 0; ct < 16; ct++) sacc[ct] = fp32x4{0,0,0,0};
  bf16x8 aF0 = *(const bf16x8*)&qs[wv * 16 + l15][quad * 8];
  bf16x8 aF1 = *(const bf16x8*)&qs[wv * 16 + l15][32 + quad * 8];
  #pragma unroll
  for (int ct = 0; ct < 16; ct++) {
    bf16x8 b0 = *(const bf16x8*)&klp[ct * 16 + l15][quad * 8];
    bf16x8 b1 = *(const bf16x8*)&klp[ct * 16 + l15][32 + quad * 8];
    sacc[ct] = __builtin_amdgcn_mfma_f32_16x16x32_bf16(aF0, b0, sacc[ct], 0, 0, 0);
    sacc[ct] = __builtin_amdgcn_mfma_f32_16x16x32_bf16(aF1, b1, sacc[ct], 0, 0, 0);
  }
  #pragma unroll
  for (int i = 0; i < 4; i++) {
    float m = -3.0e38f;
    #pragma unroll
    for (int ct = 0; ct < 16; ct++) m = fmaxf(m, sacc[ct][i]);
    #pragma unroll
    for (int o = 1; o < 16; o <<= 1) m = fmaxf(m, __shfl_xor(m, o));
    float s = 0.f;
    #pragma unroll
    for (int ct = 0; ct < 16; ct++) {
      float e = __expf(sacc[ct][i] - m);
      sacc[ct][i] = e;
      s += e;
    }
    #pragma unroll
    for (int o = 1; o < 16; o <<= 1) s += __shfl_xor(s, o);
    float inv = 1.f / s;
    #pragma unroll
    for (int ct = 0; ct < 16; ct++) sacc[ct][i] *= inv;
  }
  __syncthreads();
  u16* P = &klp[0][0];
  #pragma unroll
  for (int ct = 0; ct < 16; ct++)
    #pragma unroll
    for (int i = 0; i < 4; i++)
      P[(size_t)(wv * 16 + quad * 4 + i) * 264 + ct * 16 + l15] = f2bf(sacc[ct][i]);
  __syncthreads();

  fp32x4 oacc[4] = {fp32x4{0,0,0,0}, fp32x4{0,0,0,0}, fp32x4{0,0,0,0}, fp32x4{0,0,0,0}};
  #pragma unroll
  for (int ks = 0; ks < 8; ks++) {
    bf16x8 aP = *(const bf16x8*)&P[(size_t)(wv * 16 + l15) * 264 + ks * 32 + quad * 8];
    #pragma unroll
    for (int ct = 0; ct < 4; ct++) {
      bf16x8 bV = *(const bf16x8*)&kvs[ct * 16 + l15][ks * 32 + quad * 8];
      oacc[ct] = __builtin_amdgcn_mfma_f32_16x16x32_bf16(aP, bV, oacc[ct], 0, 0, 0);
    }
  }
  __syncthreads();
  float* osm = (float*)&klp[0][0];
  #pragma unroll
  for (int ct = 0; ct < 4; ct++)
    #pragma unroll
    for (int i = 0; i < 4; i++)
      osm[(size_t)(wv * 16 + quad * 4 + i) * 66 + ct * 16 + l15] = oacc[ct][i];
  float* vwin = (float*)&kvs[0][0];
  #pragma unroll
  for (int i = 0; i < 6; i++) {
    int r = i * 16 + (tid >> 4), c = (tid & 15) * 4;
    int g = n0 - 16 + r;
    float4 vv;
    if (g <= NPAD - 1) {
      bf16x4 bv = *(const bf16x4*)&vb[(size_t)g * DH + c];
      vv.x = bf2f((unsigned short)bv[0]); vv.y = bf2f((unsigned short)bv[1]);
      vv.z = bf2f((unsigned short)bv[2]); vv.w = bf2f((unsigned short)bv[3]);
    } else { vv.x = 0.f; vv.y = 0.f; vv.z = 0.f; vv.w = 0.f; }
    *(float4*)&vwin[r * 68 + c] = vv;
  }
  __syncthreads();
  {
    int c = tid & 63, rg = tid >> 6;
    float w[33];
    #pragma unroll
    for (int t = 0; t < 33; t++) w[t] = wsm[t];
    float a16[16];
    #pragma unroll
    for (int r = 0; r < 16; r++) a16[r] = osm[(size_t)(rg * 16 + r) * 66 + c];
    const float* vcol = &vwin[(size_t)(rg * 16) * 68 + c];
    #pragma unroll
    for (int j = 0; j < 48; j++) {
      float vj = vcol[(size_t)j * 68];
      #pragma unroll
      for (int r = 0; r < 16; r++) {
        int t = j - r;
        if (t >= 0 && t < 33) a16[r] += vj * w[t];
      }
    }
    int rowg = n0 + rg * 16;
    #pragma unroll
    for (int r = 0; r < 16; r++) {
      int n = rowg + r;
      if (n > NPAD - 1) continue;
      attn[((size_t)b * NTOK + (n - 255)) * EMBED + hh * DH + c] = f2bf(a16[r]);
    }
  }
}

// combine 7x7 + 5x5 + 3x3 + identity into one 7x7 depthwise kernel
__global__ void prep_wcomb_kernel(
    const float* __restrict__ pw7, const float* __restrict__ pw5,
    const float* __restrict__ pw3, const float* __restrict__ pb7,
    const float* __restrict__ pb5, const float* __restrict__ pb3,
    float* __restrict__ wcomb, float* __restrict__ biasc)
{
  int i = blockIdx.x * blockDim.x + threadIdx.x;
  if (i < EMBED * 49) {
    int c = i / 49, tap = i % 49;
    int ky = tap / 7, kx = tap % 7;
    float v = pw7[c * 49 + tap];
    if (ky >= 1 && ky <= 5 && kx >= 1 && kx <= 5) v += pw5[c * 25 + (ky - 1) * 5 + (kx - 1)];
    if (ky >= 2 && ky <= 4 && kx >= 2 && kx <= 4) v += pw3[c * 9 + (ky - 2) * 3 + (kx - 2)];
    if (ky == 3 && kx == 3) v += 1.f;
    wcomb[tap * EMBED + c] = v;
  }
  if (i < EMBED) biasc[i] = pb7[i] + pb5[i] + pb3[i];
}

// register-sliding-window depthwise conv:
// thread = one channel-pair (float2) x 16 x-positions x 1 row.
__global__ __launch_bounds__(256) void dwconv_kernel(
    const float* __restrict__ tmp, const float* __restrict__ wcomb,
    const float* __restrict__ biasc, float* __restrict__ h)
{
  int lane = threadIdx.x & 63;
  int xt = threadIdx.x >> 6;          // 0..3  (wave id -> wave-uniform branches)
  int cg = blockIdx.x;                 // 0..3 channel groups of 128
  int y  = blockIdx.y;                 // 0..63
  int b  = blockIdx.z;                 // 0..3
  int c  = cg * 128 + lane * 2;
  int x0 = xt * 16;
  const float* src = tmp + (size_t)b * N0 * EMBED + c;
  float2 bias = *(const float2*)&biasc[c];
  float2 acc[16];
  #pragma unroll
  for (int i = 0; i < 16; i++) acc[i] = bias;
  #pragma unroll
  for (int r = 0; r < 7; r++) {
    int row = y + r - 3;
    if (row < 0 || row >= 64) continue;           // block-uniform
    float2 w2[7];
    #pragma unroll
    for (int kx = 0; kx < 7; kx++)
      w2[kx] = *(const float2*)&wcomb[(size_t)(r * 7 + kx) * EMBED + c];
    float2 win[22];
    #pragma unroll
    for (int j = 0; j < 22; j++) {
      int xx = x0 + j - 3;
      if (xx >= 0 && xx < 64)                     // wave-uniform
        win[j] = *(const float2*)&src[((size_t)row * 64 + xx) * EMBED];
      else { win[j].x = 0.f; win[j].y = 0.f; }
    }
    #pragma unroll
    for (int kx = 0; kx < 7; kx++)
      #pragma unroll
      for (int i = 0; i < 16; i++) {
        acc[i].x += win[i + kx].x * w2[kx].x;
        acc[i].y += win[i + kx].y * w2[kx].y;
      }
  }
  float* dst = h + ((size_t)b * NTOK + 1 + (size_t)y * 64) * EMBED + c;
  #pragma unroll
  for (int i = 0; i < 16; i++)
    *(float2*)&dst[(size_t)(x0 + i) * EMBED] = acc[i];
}

__global__ __launch_bounds__(256) void final_kernel(
    const float* __restrict__ h, const float* __restrict__ g,
    const float* __restrict__ be, const float* __restrict__ W2,
    const float* __restrict__ b2, float* __restrict__ out)
{
  __shared__ float red[4];
  int b = blockIdx.x, tid = threadIdx.x;
  const float* x = h + (size_t)b * NTOK * EMBED;
  float v0 = x[tid], v1 = x[tid + 256];
  float mu = block_sum(v0 + v1, red) * (1.f / 512.f);
  float d0 = v0 - mu, d1 = v1 - mu;
  float var = block_sum(d0 * d0 + d1 * d1, red) * (1.f / 512.f);
  float inv = 1.f / sqrtf(var + 1e-5f);
  float xn0 = d0 * inv * g[tid] + be[tid];
  float xn1 = d1 * inv * g[tid + 256] + be[tid + 256];
  float l0 = block_sum(xn0 * W2[tid] + xn1 * W2[tid + 256], red);
  float l1 = block_sum(xn0 * W2[512 + tid] + xn1 * W2[512 + tid + 256], red);
  if (tid == 0) {
    l0 += b2[0]; l1 += b2[1];
    out[b * 2 + 0] = l0;
    out[b * 2 + 1] = l1;
    float mx = fmaxf(l0, l1);
    float e0 = expf(l0 - mx), e1 = expf(l1 - mx);
    float s = e0 + e1;
    out[8 + b * 2 + 0] = e0 / s;
    out[8 + b * 2 + 1] = e1 / s;
    out[16 + b] = (l1 > l0) ? 1.f : 0.f;
  }
}

// ------------------------------- host side -----------------------------------
extern "C" void kernel_launch(void* const* d_in, const int* in_sizes, int n_in,
                              void* d_out, int out_size, void* d_ws, size_t ws_size,
                              hipStream_t stream)
{
  const float* data = (const float*)d_in[0];
  const float* W1   = (const float*)d_in[1];
  const float* b1   = (const float*)d_in[2];
  const float* cls  = (const float*)d_in[3];
  const float* lng[2]  = {(const float*)d_in[4],  (const float*)d_in[10]};
  const float* lnb[2]  = {(const float*)d_in[5],  (const float*)d_in[11]};
  const float* Wqkv[2] = {(const float*)d_in[6],  (const float*)d_in[12]};
  const float* Wo[2]   = {(const float*)d_in[7],  (const float*)d_in[13]};
  const float* bo[2]   = {(const float*)d_in[8],  (const float*)d_in[14]};
  const float* resw[2] = {(const float*)d_in[9],  (const float*)d_in[15]};
  const float* pw7 = (const float*)d_in[16];
  const float* pb7 = (const float*)d_in[17];
  const float* pw5 = (const float*)d_in[18];
  const float* pb5 = (const float*)d_in[19];
  const float* pw3 = (const float*)d_in[20];
  const float* pb3 = (const float*)d_in[21];
  const float* lnfg = (const float*)d_in[22];
  const float* lnfb = (const float*)d_in[23];
  const float* W2  = (const float*)d_in[24];
  const float* b2  = (const float*)d_in[25];

  float* ws = (float*)d_ws;
  size_t off = 0;
  auto alloc = [&](size_t n) { float* p = ws + off; off += n; return p; };
  float* hbuf   = alloc((size_t)BATCH * NTOK * EMBED);          // fp32
  float* xpadf  = alloc((size_t)BATCH * NPAD * EMBED);          // bf16 (half) + attn reuse
  float* qbuff  = alloc((size_t)BH * NPAD * DH);                // q bf16 / databf / conv tmp fp32
  float* kbuff  = alloc((size_t)BH * NPAD * DH);                // k bf16 (half) + databf tail
  float* vbuff  = alloc((size_t)BH * NPAD * DH);                // v bf16 (half) + W1bf tail
  float* qland  = alloc((size_t)BH * MM * DH);
  float* kland  = alloc((size_t)BH * MM * DH);
  float* a2f    = alloc((size_t)BH * MM * MM / 2);              // bf16
  float* zaRf   = alloc((size_t)BH * MM * MM / 2);
  float* zaCf   = alloc((size_t)BH * MM * MM / 2);
  float* zbRf   = alloc((size_t)BH * MM * MM / 2);
  float* zbCf   = alloc((size_t)BH * MM * MM / 2);
  float* xzRf   = alloc((size_t)BH * MM * MM / 2);
  float* xzCf   = alloc((size_t)BH * MM * MM / 2);
  float* t1Cf   = alloc((size_t)BH * MM * MM / 2);
  float* t2Cf   = alloc((size_t)BH * MM * MM / 2);
  float* kvTf   = alloc((size_t)BH * MM * DH / 2);
  float* kv2Tf  = alloc((size_t)BH * MM * DH / 2);
  float* wqkvbf = alloc((size_t)2 * 3 * EMBED * EMBED / 2);     // bf16 x2 layers
  float* wobf   = alloc((size_t)2 * EMBED * EMBED / 2);
  float* wcomb  = alloc(49 * EMBED);
  float* biasc  = alloc(EMBED);
  float* denoms = alloc(64);
  float* mpart  = alloc((size_t)NSEG * BH * MM);
  float* lpart  = alloc((size_t)NSEG * BH * MM);

  u16* xpadB = (u16*)xpadf;
  u16* qB = (u16*)qbuff;
  u16* kB = (u16*)kbuff;
  u16* vB = (u16*)vbuff;
  u16* a2B = (u16*)a2f;
  u16* zaR = (u16*)zaRf; u16* zaC = (u16*)zaCf;
  u16* zbR = (u16*)zbRf; u16* zbC = (u16*)zbCf;
  u16* xzR = (u16*)xzRf; u16* xzC = (u16*)xzCf;
  u16* t1C = (u16*)t1Cf; u16* t2C = (u16*)t2Cf;
  u16* kvT = (u16*)kvTf; u16* kv2T = (u16*)kv2Tf;
  u16* attnB = xpadB;
  u16* OpartB = zaR;                       // overlay: free until z0_trans
  u16* databf = (u16*)qbuff;               // overlay: consumed by input GEMM only
  u16* W1bf = (u16*)vbuff;                 // overlay: consumed by input GEMM only
  u16* WqkvB[2] = {(u16*)wqkvbf, (u16*)wqkvbf + (size_t)3 * EMBED * EMBED};
  u16* WoB[2]   = {(u16*)wobf,   (u16*)wobf + (size_t)EMBED * EMBED};
  float* convtmp = qbuff;

  // ---- one-time bf16 conversions ----
  int ndata = BATCH * N0 * CIN;
  f2bf_kernel<<<dim3((ndata / 8 + 255) / 256), 256, 0, stream>>>(data, databf, ndata);
  f2bf_kernel<<<dim3((EMBED * CIN / 8 + 255) / 256), 256, 0, stream>>>(W1, W1bf, EMBED * CIN);
  // both layers' Wqkv + Wo in one launch
  f2bfw_kernel<<<dim3((3 * EMBED * EMBED / 8 + 255) / 256, 4), 256, 0, stream>>>(
      Wqkv[0], Wqkv[1], Wo[0], Wo[1], WqkvB[0], WqkvB[1], WoB[0], WoB[1],
      3 * EMBED * EMBED, 3 * EMBED * EMBED, EMBED * EMBED, EMBED * EMBED);
  init_denom_kernel<<<1, 64, 0, stream>>>(denoms);

  gemm_abt<<<dim3(EMBED / 128, (BATCH * N0) / 64), 256, 0, stream>>>(
      databf, W1bf, BATCH * N0, EMBED, CIN, b1, hbuf, nullptr, nullptr, nullptr, nullptr, 0);
  cls_kernel<<<dim3((BATCH * EMBED + 255) / 256), 256, 0, stream>>>(cls, hbuf);

  for (int layer = 0; layer < 2; layer++) {
    float* dn = denoms + layer * 2;
    ln_pad_kernel<<<dim3(BATCH * NPAD), 256, 0, stream>>>(hbuf, lng[layer], lnb[layer], xpadB);
    gemm_abt<<<dim3((3 * EMBED) / 128, (BATCH * NPAD) / 64), 256, 0, stream>>>(
        xpadB, WqkvB[layer], BATCH * NPAD, 3 * EMBED, EMBED, nullptr,
        nullptr, nullptr, qB, kB, vB, 1);
    landmarks_kernel<<<dim3(MM / 4, BH), 256, 0, stream>>>(qB, kB, qland, kland);
    s2_softmax_kernel<<<dim3(MM, BH), 256, 0, stream>>>(qland, kland, a2B);
    denom_kernel<<<dim3(BH), 256, 0, stream>>>(a2B, dn);

    // a3@v before pinv so Opart can overlay the pinv scratch
    a3v_part_mfma<<<dim3(4 * NSEG, BH), 256, 0, stream>>>(
        qland, kB, vB, OpartB, mpart, lpart);
    a3v_merge_kernel<<<dim3(MM / 64, BH), 256, 0, stream>>>(OpartB, mpart, lpart, kvT);

    z0_trans_kernel<<<dim3(4, 4, BH), 256, 0, stream>>>(a2B, dn, zaR, zaC);
    u16 *zinR = zaR, *zinC = zaC, *zoutR = zbR, *zoutC = zbC;
    for (int it = 0; it < 6; it++) {
      // y = a2 @ z  -> yR (xzR), yC (xzC)
      gemm_nn2<<<dim3(4, 4, BH), 256, 0, stream>>>(a2B, zinC, xzR, xzC, MM, 0.f, 1.f, 1.f);
      // u = 7y - y@y -> uC (t1C)   ||   w = z@y -> wR (t2C)   (one launch)
      gemm_pair<<<dim3(4, 8, BH), 256, 0, stream>>>(xzR, zinR, xzC, t1C, t2C);
      // z' = 0.25*(w@u - 15w + 13z)
      gemm_zstep<<<dim3(4, 4, BH), 256, 0, stream>>>(t2C, t1C, zinR, zoutR, zoutC);
      u16* t;
      t = zinR; zinR = zoutR; zoutR = t;
      t = zinC; zinC = zoutC; zoutC = t;
    }
    // kv2T[dh][m] = (z @ kv)^T
    gemm_nn2<<<dim3(1, 4, BH), 256, 0, stream>>>(zinR, kvT, nullptr, kv2T, DH, 0.f, 1.f, 1.f);
    attn1_mfma<<<dim3((NTOK + 63) / 64, BH), 256, 0, stream>>>(
        qB, kland, kv2T, vB, resw[layer], attnB);
    gemm_abt<<<dim3(EMBED / 128, (BATCH * NTOK + 63) / 64), 256, 0, stream>>>(
        attnB, WoB[layer], BATCH * NTOK, EMBED, EMBED, bo[layer], hbuf,
        (layer == 0) ? convtmp : nullptr, nullptr, nullptr, nullptr,
        (layer == 0) ? 3 : 2);

    if (layer == 0) {
      prep_wcomb_kernel<<<dim3((EMBED * 49 + 255) / 256), 256, 0, stream>>>(
          pw7, pw5, pw3, pb7, pb5, pb3, wcomb, biasc);
      dwconv_kernel<<<dim3(4, 64, BATCH), 256, 0, stream>>>(
          convtmp, wcomb, biasc, hbuf);
    }
  }

  final_kernel<<<dim3(BATCH), 256, 0, stream>>>(hbuf, lnfg, lnfb, W2, b2, (float*)d_out);
}